// Round 1
// baseline (2344.406 us; speedup 1.0000x reference)
//
#include <hip/hip_runtime.h>
#include <hip/hip_bf16.h>
#include <math.h>

// Problem constants (fixed by the reference file)
#define NPTS 262144
#define NP   128
#define DD   64
#define NWORDS (NPTS / 64)   // 4096 u64 ballot words per plane

// ---------------------------------------------------------------------------
// Kernel 1: per-point MLP (fc1 -> BN+ReLU -> fc2 -> BN+ReLU -> fc3 -> ReLU)
// fp32 vector ALU (no fp32 MFMA on CDNA4; bf16 would flip sigmoid boundary).
// Weights are indexed wave-uniformly -> compiler emits s_load + v_fmac(SGPR).
// ---------------------------------------------------------------------------
__global__ __launch_bounds__(256) void mlp_kernel(
    const float* __restrict__ feature, const float* __restrict__ feature_geo,
    const float* __restrict__ w1, const float* __restrict__ b1,
    const float* __restrict__ g1, const float* __restrict__ be1,
    const float* __restrict__ m1, const float* __restrict__ v1,
    const float* __restrict__ w2, const float* __restrict__ b2,
    const float* __restrict__ g2, const float* __restrict__ be2,
    const float* __restrict__ m2, const float* __restrict__ v2,
    const float* __restrict__ w3, const float* __restrict__ b3,
    float* __restrict__ h2_out, float* __restrict__ scores_out)
{
    const int n = blockIdx.x * 256 + threadIdx.x;
    float f[DD], acc[DD];
#pragma unroll
    for (int j = 0; j < DD; ++j) acc[j] = 0.0f;

    // fc1 first half: feature
    {
        const float4* fp = reinterpret_cast<const float4*>(feature) + (size_t)n * 16;
#pragma unroll
        for (int q = 0; q < 16; ++q) {
            float4 v = fp[q];
            f[4*q+0] = v.x; f[4*q+1] = v.y; f[4*q+2] = v.z; f[4*q+3] = v.w;
        }
    }
#pragma unroll
    for (int k = 0; k < DD; ++k) {
        const float* wr = w1 + k * DD;
#pragma unroll
        for (int j = 0; j < DD; ++j) acc[j] = fmaf(f[k], wr[j], acc[j]);
    }
    // fc1 second half: feature_geo (reuse f regs)
    {
        const float4* fp = reinterpret_cast<const float4*>(feature_geo) + (size_t)n * 16;
#pragma unroll
        for (int q = 0; q < 16; ++q) {
            float4 v = fp[q];
            f[4*q+0] = v.x; f[4*q+1] = v.y; f[4*q+2] = v.z; f[4*q+3] = v.w;
        }
    }
#pragma unroll
    for (int k = 0; k < DD; ++k) {
        const float* wr = w1 + (DD + k) * DD;
#pragma unroll
        for (int j = 0; j < DD; ++j) acc[j] = fmaf(f[k], wr[j], acc[j]);
    }
    // BN1 + ReLU -> f (h1)
#pragma unroll
    for (int j = 0; j < DD; ++j) {
        float sc = g1[j] * (1.0f / sqrtf(v1[j] + 1e-5f));
        float h  = fmaf(acc[j] + b1[j] - m1[j], sc, be1[j]);
        f[j]   = fmaxf(h, 0.0f);
        acc[j] = 0.0f;
    }
    // fc2
#pragma unroll
    for (int k = 0; k < DD; ++k) {
        const float* wr = w2 + k * DD;
#pragma unroll
        for (int j = 0; j < DD; ++j) acc[j] = fmaf(f[k], wr[j], acc[j]);
    }
    // BN2 + ReLU -> f (h2), fused fc3 dot
    float s = 0.0f;
#pragma unroll
    for (int j = 0; j < DD; ++j) {
        float sc = g2[j] * (1.0f / sqrtf(v2[j] + 1e-5f));
        float h  = fmaf(acc[j] + b2[j] - m2[j], sc, be2[j]);
        h = fmaxf(h, 0.0f);
        f[j] = h;
        s = fmaf(h, w3[j], s);
    }
    s += b3[0];
    const float score = fmaxf(s, 0.0f);

    // store h2 (row-major [N][64]) + score
    float4* o = reinterpret_cast<float4*>(h2_out) + (size_t)n * 16;
#pragma unroll
    for (int q = 0; q < 16; ++q)
        o[q] = make_float4(f[4*q+0], f[4*q+1], f[4*q+2], f[4*q+3]);
    scores_out[n] = score;
}

// ---------------------------------------------------------------------------
// Kernel 2: per-(plane,point) masks + scores_masked + ballot-compacted hit
// bitmasks for the pooling kernel. Write-bandwidth bound (537 MB of stores).
// ---------------------------------------------------------------------------
__global__ __launch_bounds__(256) void mask_kernel(
    const float* __restrict__ xyz, const float* __restrict__ centers,
    const float* __restrict__ plane_center, const float* __restrict__ plane_normal,
    const float* __restrict__ pmin, const float* __restrict__ pmax,
    const float* __restrict__ scores,
    float* __restrict__ out_sm, float* __restrict__ out_mask,
    float* __restrict__ out_on, float* __restrict__ out_off,
    unsigned long long* __restrict__ hitOn, unsigned long long* __restrict__ hitOff)
{
    __shared__ float4 pl[NP][3];   // [normal.xyz, offs], [min.xyz, -], [max.xyz, -]
    const int t = threadIdx.x;
    if (t < NP) {
        float n0 = plane_normal[t*3+0], n1 = plane_normal[t*3+1], n2 = plane_normal[t*3+2];
        float c0 = plane_center[t*3+0], c1 = plane_center[t*3+1], c2 = plane_center[t*3+2];
        float off = (c0*n0 + c1*n1) + c2*n2;          // matches jnp.sum order
        pl[t][0] = make_float4(n0, n1, n2, off);
        pl[t][1] = make_float4(pmin[t*3+0], pmin[t*3+1], pmin[t*3+2], 0.0f);
        pl[t][2] = make_float4(pmax[t*3+0], pmax[t*3+1], pmax[t*3+2], 0.0f);
    }
    __syncthreads();

    const int n = blockIdx.x * 256 + t;
    const float c0 = xyz[n*3+0] + centers[0];
    const float c1 = xyz[n*3+1] + centers[1];
    const float c2 = xyz[n*3+2] + centers[2];
    const float s  = scores[n];
    // sigmoid(s) > 0.5 via XLA-style logistic expansion (s >= 0 post-ReLU)
    const bool on  = (0.5f + 0.5f * tanhf(0.5f * s)) > 0.5f;
    const int lane = t & 63;
    const int word = n >> 6;

    for (int p = 0; p < NP; ++p) {
        float4 nrm = pl[p][0];
        float4 mn  = pl[p][1];
        float4 mx  = pl[p][2];
        float d = fabsf(fmaf(c2, nrm.z, fmaf(c1, nrm.y, c0 * nrm.x)) - nrm.w);
        bool ok0 = (mx.x == 0.0f) | ((c0 >= mn.x) & (c0 < mx.x));
        bool ok1 = (mx.y == 0.0f) | ((c1 >= mn.y) & (c1 < mx.y));
        bool ok2 = (mx.z == 0.0f) | ((c2 >= mn.z) & (c2 < mx.z));
        bool mk  = ok0 & ok1 & ok2 & (d < 0.1f);
        size_t idx = (size_t)p * NPTS + n;
        out_sm[idx]   = mk ? s : 0.0f;
        out_mask[idx] = mk ? 1.0f : 0.0f;
        bool mon  = mk & on;
        bool moff = mk & (!on);
        out_on[idx]  = mon  ? 1.0f : 0.0f;
        out_off[idx] = moff ? 1.0f : 0.0f;
        unsigned long long bOn  = __ballot(mon);
        unsigned long long bOff = __ballot(moff);
        if (lane == 0) {
            hitOn [(size_t)p * NWORDS + word] = bOn;
            hitOff[(size_t)p * NWORDS + word] = bOff;
        }
    }
}

// ---------------------------------------------------------------------------
// Kernel 3: pooling partials. Block = 256 thr, 4 chunks of 128 points.
// Wave w owns planes [32w,32w+32); lane = dim. Hit loop is wave-uniform
// (bitmask broadcast from LDS) -> dense fmax, no divergence waste.
// tile[n*64+lane]: 64 lanes over 32 banks = 2-way alias = free (m136).
// h2 >= 0, so 0-init == jnp.where(any(m), max, 0) semantics.
// ---------------------------------------------------------------------------
__global__ __launch_bounds__(256) void pool_kernel(
    const float* __restrict__ h2,
    const unsigned long long* __restrict__ hitOn,
    const unsigned long long* __restrict__ hitOff,
    float* __restrict__ partials)
{
    __shared__ float tile[128 * DD];                 // 32 KB
    __shared__ unsigned long long bm[2][NP][2];      // 4 KB  [on/off][plane][word]
    const int t = threadIdx.x;
    const int lane = t & 63;
    const int wv = t >> 6;

    float accOn[32], accOff[32];
#pragma unroll
    for (int i = 0; i < 32; ++i) { accOn[i] = 0.0f; accOff[i] = 0.0f; }

    for (int cc = 0; cc < 4; ++cc) {
        const int chunk = blockIdx.x * 4 + cc;       // 0..2047
        const int base  = chunk * 128;
        // stage h2 tile (coalesced float4)
        const float4* src = reinterpret_cast<const float4*>(h2 + (size_t)base * DD);
        float4* dst = reinterpret_cast<float4*>(tile);
#pragma unroll
        for (int q = 0; q < 8; ++q) dst[t + q * 256] = src[t + q * 256];
        // stage ballot words for this chunk
        {
            const int p = t & 127;
            const int half = t >> 7;
            const unsigned long long* hsrc = half ? hitOff : hitOn;
            const int w0 = chunk * 2;
            bm[half][p][0] = hsrc[(size_t)p * NWORDS + w0 + 0];
            bm[half][p][1] = hsrc[(size_t)p * NWORDS + w0 + 1];
        }
        __syncthreads();

#pragma unroll
        for (int i = 0; i < 32; ++i) {
            const int p = wv * 32 + i;
            unsigned long long m;
            m = bm[0][p][0];
            while (m) { int nn = __builtin_ctzll(m); m &= m - 1;
                        accOn[i]  = fmaxf(accOn[i],  tile[nn * DD + lane]); }
            m = bm[0][p][1];
            while (m) { int nn = __builtin_ctzll(m); m &= m - 1;
                        accOn[i]  = fmaxf(accOn[i],  tile[(64 + nn) * DD + lane]); }
            m = bm[1][p][0];
            while (m) { int nn = __builtin_ctzll(m); m &= m - 1;
                        accOff[i] = fmaxf(accOff[i], tile[nn * DD + lane]); }
            m = bm[1][p][1];
            while (m) { int nn = __builtin_ctzll(m); m &= m - 1;
                        accOff[i] = fmaxf(accOff[i], tile[(64 + nn) * DD + lane]); }
        }
        __syncthreads();
    }
    // partials layout: [block][plane][on/off][dim]
    const size_t bbase = (size_t)blockIdx.x * NP * 2 * DD;
#pragma unroll
    for (int i = 0; i < 32; ++i) {
        const int p = wv * 32 + i;
        partials[bbase + ((size_t)p * 2 + 0) * DD + lane] = accOn[i];
        partials[bbase + ((size_t)p * 2 + 1) * DD + lane] = accOff[i];
    }
}

// ---------------------------------------------------------------------------
// Kernel 4: reduce partials over 512 blocks -> on_feat/off_feat [P][64]
// ---------------------------------------------------------------------------
__global__ __launch_bounds__(256) void reduce_kernel(
    const float* __restrict__ partials, float* __restrict__ out_feats)
{
    const int u = blockIdx.x * 256 + threadIdx.x;    // 0..16383 = p*128+oo*64+d
    float a0 = 0.0f, a1 = 0.0f, a2 = 0.0f, a3 = 0.0f;
    for (int b = 0; b < 512; b += 4) {
        a0 = fmaxf(a0, partials[(size_t)(b + 0) * 16384 + u]);
        a1 = fmaxf(a1, partials[(size_t)(b + 1) * 16384 + u]);
        a2 = fmaxf(a2, partials[(size_t)(b + 2) * 16384 + u]);
        a3 = fmaxf(a3, partials[(size_t)(b + 3) * 16384 + u]);
    }
    const float acc = fmaxf(fmaxf(a0, a1), fmaxf(a2, a3));
    const int p = u >> 7, oo = (u >> 6) & 1, d = u & 63;
    out_feats[oo * (NP * DD) + p * DD + d] = acc;    // on_feat then off_feat
}

extern "C" void kernel_launch(void* const* d_in, const int* in_sizes, int n_in,
                              void* d_out, int out_size, void* d_ws, size_t ws_size,
                              hipStream_t stream) {
    const float* feature      = (const float*)d_in[0];
    const float* feature_geo  = (const float*)d_in[1];
    const float* xyz          = (const float*)d_in[2];
    const float* centers      = (const float*)d_in[3];
    const float* plane_center = (const float*)d_in[4];
    const float* plane_normal = (const float*)d_in[5];
    const float* pmin         = (const float*)d_in[6];
    const float* pmax         = (const float*)d_in[7];
    const float* w1 = (const float*)d_in[8];
    const float* b1 = (const float*)d_in[9];
    const float* g1 = (const float*)d_in[10];
    const float* be1 = (const float*)d_in[11];
    const float* m1 = (const float*)d_in[12];
    const float* v1 = (const float*)d_in[13];
    const float* w2 = (const float*)d_in[14];
    const float* b2 = (const float*)d_in[15];
    const float* g2 = (const float*)d_in[16];
    const float* be2 = (const float*)d_in[17];
    const float* m2 = (const float*)d_in[18];
    const float* v2 = (const float*)d_in[19];
    const float* w3 = (const float*)d_in[20];
    const float* b3 = (const float*)d_in[21];

    float* out = (float*)d_out;
    const size_t PN = (size_t)NP * NPTS;
    float* out_sm    = out;
    float* out_mask  = out + PN;
    float* out_on    = out + 2 * PN;
    float* out_off   = out + 3 * PN;
    float* out_feats = out + 4 * PN;

    // workspace carve (~105 MB total)
    float* h2     = (float*)d_ws;                                // N*64 f32
    float* scores = h2 + (size_t)NPTS * DD;                      // N f32
    unsigned long long* hitOn  = (unsigned long long*)(scores + NPTS);
    unsigned long long* hitOff = hitOn + (size_t)NP * NWORDS;
    float* partials = (float*)(hitOff + (size_t)NP * NWORDS);    // 512*128*2*64 f32

    mlp_kernel<<<NPTS / 256, 256, 0, stream>>>(
        feature, feature_geo, w1, b1, g1, be1, m1, v1,
        w2, b2, g2, be2, m2, v2, w3, b3, h2, scores);
    mask_kernel<<<NPTS / 256, 256, 0, stream>>>(
        xyz, centers, plane_center, plane_normal, pmin, pmax, scores,
        out_sm, out_mask, out_on, out_off, hitOn, hitOff);
    pool_kernel<<<512, 256, 0, stream>>>(h2, hitOn, hitOff, partials);
    reduce_kernel<<<16384 / 256, 256, 0, stream>>>(partials, out_feats);
}

// Round 2
// 892.561 us; speedup vs baseline: 2.6266x; 2.6266x over previous
//
#include <hip/hip_runtime.h>
#include <hip/hip_bf16.h>
#include <math.h>

// Problem constants (fixed by the reference file)
#define NPTS 262144
#define NP   128
#define DD   64
#define NWORDS (NPTS / 64)   // 4096 u64 ballot words per plane

// ---------------------------------------------------------------------------
// MLP stage 1: fc1 (128->64) + BN1 + ReLU -> h1 (ws).
// K-loop rolled (#pragma unroll 1) so code ~2 KB fits I$ (round-1 failure was
// ~60+ KB unrolled body thrashing the 32 KB I$: VALUBusy 34%, occ 12%).
// Weight addresses are wave-uniform (loop var q, constant j) -> s_load;
// FMA = v_fmac_f32 v_acc, s_w, v_f (SGPR operand free).
// Activations: float4 per 4-k body = 16 B/lane coalesced, single-use.
// ---------------------------------------------------------------------------
__global__ __launch_bounds__(256) void mlp1_kernel(
    const float* __restrict__ feature, const float* __restrict__ feature_geo,
    const float* __restrict__ w1, const float* __restrict__ b1,
    const float* __restrict__ g1, const float* __restrict__ be1,
    const float* __restrict__ m1, const float* __restrict__ v1,
    float* __restrict__ h1_out)
{
    const int n = blockIdx.x * 256 + threadIdx.x;
    float acc[DD];
#pragma unroll
    for (int j = 0; j < DD; ++j) acc[j] = 0.0f;

    const float4* fA = reinterpret_cast<const float4*>(feature) + (size_t)n * 16;
#pragma unroll 1
    for (int q = 0; q < 16; ++q) {
        const float4 fv = fA[q];
        const float* wr = w1 + q * 4 * DD;
#pragma unroll
        for (int j = 0; j < DD; ++j) acc[j] = fmaf(fv.x, wr[j], acc[j]);
#pragma unroll
        for (int j = 0; j < DD; ++j) acc[j] = fmaf(fv.y, wr[DD + j], acc[j]);
#pragma unroll
        for (int j = 0; j < DD; ++j) acc[j] = fmaf(fv.z, wr[2 * DD + j], acc[j]);
#pragma unroll
        for (int j = 0; j < DD; ++j) acc[j] = fmaf(fv.w, wr[3 * DD + j], acc[j]);
    }
    const float4* fB = reinterpret_cast<const float4*>(feature_geo) + (size_t)n * 16;
    const float* w1b = w1 + DD * DD;
#pragma unroll 1
    for (int q = 0; q < 16; ++q) {
        const float4 fv = fB[q];
        const float* wr = w1b + q * 4 * DD;
#pragma unroll
        for (int j = 0; j < DD; ++j) acc[j] = fmaf(fv.x, wr[j], acc[j]);
#pragma unroll
        for (int j = 0; j < DD; ++j) acc[j] = fmaf(fv.y, wr[DD + j], acc[j]);
#pragma unroll
        for (int j = 0; j < DD; ++j) acc[j] = fmaf(fv.z, wr[2 * DD + j], acc[j]);
#pragma unroll
        for (int j = 0; j < DD; ++j) acc[j] = fmaf(fv.w, wr[3 * DD + j], acc[j]);
    }
    // BN1 + ReLU
#pragma unroll
    for (int j = 0; j < DD; ++j) {
        float sc = g1[j] * (1.0f / sqrtf(v1[j] + 1e-5f));
        float h  = fmaf(acc[j] + b1[j] - m1[j], sc, be1[j]);
        acc[j] = fmaxf(h, 0.0f);
    }
    float4* o = reinterpret_cast<float4*>(h1_out) + (size_t)n * 16;
#pragma unroll
    for (int q = 0; q < 16; ++q)
        o[q] = make_float4(acc[4*q+0], acc[4*q+1], acc[4*q+2], acc[4*q+3]);
}

// ---------------------------------------------------------------------------
// MLP stage 2: fc2 (64->64) + BN2 + ReLU -> h2; fc3 (64->1) + ReLU -> score.
// ---------------------------------------------------------------------------
__global__ __launch_bounds__(256) void mlp2_kernel(
    const float* __restrict__ h1_in,
    const float* __restrict__ w2, const float* __restrict__ b2,
    const float* __restrict__ g2, const float* __restrict__ be2,
    const float* __restrict__ m2, const float* __restrict__ v2,
    const float* __restrict__ w3, const float* __restrict__ b3,
    float* __restrict__ h2_out, float* __restrict__ scores_out)
{
    const int n = blockIdx.x * 256 + threadIdx.x;
    float acc[DD];
#pragma unroll
    for (int j = 0; j < DD; ++j) acc[j] = 0.0f;

    const float4* fA = reinterpret_cast<const float4*>(h1_in) + (size_t)n * 16;
#pragma unroll 1
    for (int q = 0; q < 16; ++q) {
        const float4 fv = fA[q];
        const float* wr = w2 + q * 4 * DD;
#pragma unroll
        for (int j = 0; j < DD; ++j) acc[j] = fmaf(fv.x, wr[j], acc[j]);
#pragma unroll
        for (int j = 0; j < DD; ++j) acc[j] = fmaf(fv.y, wr[DD + j], acc[j]);
#pragma unroll
        for (int j = 0; j < DD; ++j) acc[j] = fmaf(fv.z, wr[2 * DD + j], acc[j]);
#pragma unroll
        for (int j = 0; j < DD; ++j) acc[j] = fmaf(fv.w, wr[3 * DD + j], acc[j]);
    }
    // BN2 + ReLU -> h2, fused fc3 dot
    float s = 0.0f;
#pragma unroll
    for (int j = 0; j < DD; ++j) {
        float sc = g2[j] * (1.0f / sqrtf(v2[j] + 1e-5f));
        float h  = fmaf(acc[j] + b2[j] - m2[j], sc, be2[j]);
        h = fmaxf(h, 0.0f);
        acc[j] = h;
        s = fmaf(h, w3[j], s);
    }
    s += b3[0];
    float4* o = reinterpret_cast<float4*>(h2_out) + (size_t)n * 16;
#pragma unroll
    for (int q = 0; q < 16; ++q)
        o[q] = make_float4(acc[4*q+0], acc[4*q+1], acc[4*q+2], acc[4*q+3]);
    scores_out[n] = fmaxf(s, 0.0f);
}

// ---------------------------------------------------------------------------
// Kernel 2: per-(plane,point) masks + scores_masked + ballot-compacted hit
// bitmasks for the pooling kernel. Write-bandwidth bound (537 MB of stores).
// ---------------------------------------------------------------------------
__global__ __launch_bounds__(256) void mask_kernel(
    const float* __restrict__ xyz, const float* __restrict__ centers,
    const float* __restrict__ plane_center, const float* __restrict__ plane_normal,
    const float* __restrict__ pmin, const float* __restrict__ pmax,
    const float* __restrict__ scores,
    float* __restrict__ out_sm, float* __restrict__ out_mask,
    float* __restrict__ out_on, float* __restrict__ out_off,
    unsigned long long* __restrict__ hitOn, unsigned long long* __restrict__ hitOff)
{
    __shared__ float4 pl[NP][3];   // [normal.xyz, offs], [min.xyz, -], [max.xyz, -]
    const int t = threadIdx.x;
    if (t < NP) {
        float n0 = plane_normal[t*3+0], n1 = plane_normal[t*3+1], n2 = plane_normal[t*3+2];
        float c0 = plane_center[t*3+0], c1 = plane_center[t*3+1], c2 = plane_center[t*3+2];
        float off = (c0*n0 + c1*n1) + c2*n2;          // matches jnp.sum order
        pl[t][0] = make_float4(n0, n1, n2, off);
        pl[t][1] = make_float4(pmin[t*3+0], pmin[t*3+1], pmin[t*3+2], 0.0f);
        pl[t][2] = make_float4(pmax[t*3+0], pmax[t*3+1], pmax[t*3+2], 0.0f);
    }
    __syncthreads();

    const int n = blockIdx.x * 256 + t;
    const float c0 = xyz[n*3+0] + centers[0];
    const float c1 = xyz[n*3+1] + centers[1];
    const float c2 = xyz[n*3+2] + centers[2];
    const float s  = scores[n];
    // sigmoid(s) > 0.5 via XLA-style logistic expansion (s >= 0 post-ReLU)
    const bool on  = (0.5f + 0.5f * tanhf(0.5f * s)) > 0.5f;
    const int lane = t & 63;
    const int word = n >> 6;

    for (int p = 0; p < NP; ++p) {
        float4 nrm = pl[p][0];
        float4 mn  = pl[p][1];
        float4 mx  = pl[p][2];
        float d = fabsf(fmaf(c2, nrm.z, fmaf(c1, nrm.y, c0 * nrm.x)) - nrm.w);
        bool ok0 = (mx.x == 0.0f) | ((c0 >= mn.x) & (c0 < mx.x));
        bool ok1 = (mx.y == 0.0f) | ((c1 >= mn.y) & (c1 < mx.y));
        bool ok2 = (mx.z == 0.0f) | ((c2 >= mn.z) & (c2 < mx.z));
        bool mk  = ok0 & ok1 & ok2 & (d < 0.1f);
        size_t idx = (size_t)p * NPTS + n;
        out_sm[idx]   = mk ? s : 0.0f;
        out_mask[idx] = mk ? 1.0f : 0.0f;
        bool mon  = mk & on;
        bool moff = mk & (!on);
        out_on[idx]  = mon  ? 1.0f : 0.0f;
        out_off[idx] = moff ? 1.0f : 0.0f;
        unsigned long long bOn  = __ballot(mon);
        unsigned long long bOff = __ballot(moff);
        if (lane == 0) {
            hitOn [(size_t)p * NWORDS + word] = bOn;
            hitOff[(size_t)p * NWORDS + word] = bOff;
        }
    }
}

// ---------------------------------------------------------------------------
// Kernel 3: pooling partials. Block = 256 thr, 4 chunks of 128 points.
// Wave w owns planes [32w,32w+32); lane = dim. Hit loop is wave-uniform
// (bitmask broadcast from LDS) -> dense fmax, no divergence waste.
// tile[n*64+lane]: 64 lanes over 32 banks = 2-way alias = free (m136).
// h2 >= 0, so 0-init == jnp.where(any(m), max, 0) semantics.
// ---------------------------------------------------------------------------
__global__ __launch_bounds__(256) void pool_kernel(
    const float* __restrict__ h2,
    const unsigned long long* __restrict__ hitOn,
    const unsigned long long* __restrict__ hitOff,
    float* __restrict__ partials)
{
    __shared__ float tile[128 * DD];                 // 32 KB
    __shared__ unsigned long long bm[2][NP][2];      // 4 KB  [on/off][plane][word]
    const int t = threadIdx.x;
    const int lane = t & 63;
    const int wv = t >> 6;

    float accOn[32], accOff[32];
#pragma unroll
    for (int i = 0; i < 32; ++i) { accOn[i] = 0.0f; accOff[i] = 0.0f; }

    for (int cc = 0; cc < 4; ++cc) {
        const int chunk = blockIdx.x * 4 + cc;       // 0..2047
        const int base  = chunk * 128;
        // stage h2 tile (coalesced float4)
        const float4* src = reinterpret_cast<const float4*>(h2 + (size_t)base * DD);
        float4* dst = reinterpret_cast<float4*>(tile);
#pragma unroll
        for (int q = 0; q < 8; ++q) dst[t + q * 256] = src[t + q * 256];
        // stage ballot words for this chunk
        {
            const int p = t & 127;
            const int half = t >> 7;
            const unsigned long long* hsrc = half ? hitOff : hitOn;
            const int w0 = chunk * 2;
            bm[half][p][0] = hsrc[(size_t)p * NWORDS + w0 + 0];
            bm[half][p][1] = hsrc[(size_t)p * NWORDS + w0 + 1];
        }
        __syncthreads();

#pragma unroll
        for (int i = 0; i < 32; ++i) {
            const int p = wv * 32 + i;
            unsigned long long m;
            m = bm[0][p][0];
            while (m) { int nn = __builtin_ctzll(m); m &= m - 1;
                        accOn[i]  = fmaxf(accOn[i],  tile[nn * DD + lane]); }
            m = bm[0][p][1];
            while (m) { int nn = __builtin_ctzll(m); m &= m - 1;
                        accOn[i]  = fmaxf(accOn[i],  tile[(64 + nn) * DD + lane]); }
            m = bm[1][p][0];
            while (m) { int nn = __builtin_ctzll(m); m &= m - 1;
                        accOff[i] = fmaxf(accOff[i], tile[nn * DD + lane]); }
            m = bm[1][p][1];
            while (m) { int nn = __builtin_ctzll(m); m &= m - 1;
                        accOff[i] = fmaxf(accOff[i], tile[(64 + nn) * DD + lane]); }
        }
        __syncthreads();
    }
    // partials layout: [block][plane][on/off][dim]
    const size_t bbase = (size_t)blockIdx.x * NP * 2 * DD;
#pragma unroll
    for (int i = 0; i < 32; ++i) {
        const int p = wv * 32 + i;
        partials[bbase + ((size_t)p * 2 + 0) * DD + lane] = accOn[i];
        partials[bbase + ((size_t)p * 2 + 1) * DD + lane] = accOff[i];
    }
}

// ---------------------------------------------------------------------------
// Kernel 4: reduce partials over 512 blocks -> on_feat/off_feat [P][64]
// ---------------------------------------------------------------------------
__global__ __launch_bounds__(256) void reduce_kernel(
    const float* __restrict__ partials, float* __restrict__ out_feats)
{
    const int u = blockIdx.x * 256 + threadIdx.x;    // 0..16383 = p*128+oo*64+d
    float a0 = 0.0f, a1 = 0.0f, a2 = 0.0f, a3 = 0.0f;
    for (int b = 0; b < 512; b += 4) {
        a0 = fmaxf(a0, partials[(size_t)(b + 0) * 16384 + u]);
        a1 = fmaxf(a1, partials[(size_t)(b + 1) * 16384 + u]);
        a2 = fmaxf(a2, partials[(size_t)(b + 2) * 16384 + u]);
        a3 = fmaxf(a3, partials[(size_t)(b + 3) * 16384 + u]);
    }
    const float acc = fmaxf(fmaxf(a0, a1), fmaxf(a2, a3));
    const int p = u >> 7, oo = (u >> 6) & 1, d = u & 63;
    out_feats[oo * (NP * DD) + p * DD + d] = acc;    // on_feat then off_feat
}

extern "C" void kernel_launch(void* const* d_in, const int* in_sizes, int n_in,
                              void* d_out, int out_size, void* d_ws, size_t ws_size,
                              hipStream_t stream) {
    const float* feature      = (const float*)d_in[0];
    const float* feature_geo  = (const float*)d_in[1];
    const float* xyz          = (const float*)d_in[2];
    const float* centers      = (const float*)d_in[3];
    const float* plane_center = (const float*)d_in[4];
    const float* plane_normal = (const float*)d_in[5];
    const float* pmin         = (const float*)d_in[6];
    const float* pmax         = (const float*)d_in[7];
    const float* w1 = (const float*)d_in[8];
    const float* b1 = (const float*)d_in[9];
    const float* g1 = (const float*)d_in[10];
    const float* be1 = (const float*)d_in[11];
    const float* m1 = (const float*)d_in[12];
    const float* v1 = (const float*)d_in[13];
    const float* w2 = (const float*)d_in[14];
    const float* b2 = (const float*)d_in[15];
    const float* g2 = (const float*)d_in[16];
    const float* be2 = (const float*)d_in[17];
    const float* m2 = (const float*)d_in[18];
    const float* v2 = (const float*)d_in[19];
    const float* w3 = (const float*)d_in[20];
    const float* b3 = (const float*)d_in[21];

    float* out = (float*)d_out;
    const size_t PN = (size_t)NP * NPTS;
    float* out_sm    = out;
    float* out_mask  = out + PN;
    float* out_on    = out + 2 * PN;
    float* out_off   = out + 3 * PN;
    float* out_feats = out + 4 * PN;

    // workspace carve (~137 MB; partials aliases h1 — h1 dead after mlp2)
    float* h1     = (float*)d_ws;                                // N*64 f32 (64 MB)
    float* h2     = h1 + (size_t)NPTS * DD;                      // N*64 f32 (64 MB)
    float* scores = h2 + (size_t)NPTS * DD;                      // N f32
    unsigned long long* hitOn  = (unsigned long long*)(scores + NPTS);
    unsigned long long* hitOff = hitOn + (size_t)NP * NWORDS;
    float* partials = h1;                                        // 512*128*2*64 f32 (33 MB, alias)

    mlp1_kernel<<<NPTS / 256, 256, 0, stream>>>(
        feature, feature_geo, w1, b1, g1, be1, m1, v1, h1);
    mlp2_kernel<<<NPTS / 256, 256, 0, stream>>>(
        h1, w2, b2, g2, be2, m2, v2, w3, b3, h2, scores);
    mask_kernel<<<NPTS / 256, 256, 0, stream>>>(
        xyz, centers, plane_center, plane_normal, pmin, pmax, scores,
        out_sm, out_mask, out_on, out_off, hitOn, hitOff);
    pool_kernel<<<512, 256, 0, stream>>>(h2, hitOn, hitOff, partials);
    reduce_kernel<<<16384 / 256, 256, 0, stream>>>(partials, out_feats);
}

// Round 3
// 869.449 us; speedup vs baseline: 2.6964x; 1.0266x over previous
//
#include <hip/hip_runtime.h>
#include <hip/hip_bf16.h>
#include <math.h>

// Problem constants (fixed by the reference file)
#define NPTS 262144
#define NP   128
#define DD   64
#define NWORDS (NPTS / 64)   // 4096 u64 ballot words per plane

// ---------------------------------------------------------------------------
// Prep: pack plane params to [P][12] floats (normal.xyz, offs | min.xyz | max.xyz)
// so mask_kernel reads them as wave-uniform float4 -> s_load_dwordx4 (SMEM pipe,
// no LDS, no barrier). Also zero out_feats (16384 floats) for the atomic-max
// pool (d_out is poisoned 0xAA before every timed launch).
// ---------------------------------------------------------------------------
__global__ __launch_bounds__(256) void prep_kernel(
    const float* __restrict__ plane_center, const float* __restrict__ plane_normal,
    const float* __restrict__ pmin, const float* __restrict__ pmax,
    float* __restrict__ packed, float* __restrict__ out_feats)
{
    const int t = threadIdx.x;
    out_feats[blockIdx.x * 256 + t] = 0.0f;          // grid = 64 blocks
    if (blockIdx.x == 0 && t < NP) {
        float n0 = plane_normal[t*3+0], n1 = plane_normal[t*3+1], n2 = plane_normal[t*3+2];
        float c0 = plane_center[t*3+0], c1 = plane_center[t*3+1], c2 = plane_center[t*3+2];
        float off = (c0*n0 + c1*n1) + c2*n2;          // matches jnp.sum order
        float4* pp = reinterpret_cast<float4*>(packed) + t * 3;
        pp[0] = make_float4(n0, n1, n2, off);
        pp[1] = make_float4(pmin[t*3+0], pmin[t*3+1], pmin[t*3+2], 0.0f);
        pp[2] = make_float4(pmax[t*3+0], pmax[t*3+1], pmax[t*3+2], 0.0f);
    }
}

// ---------------------------------------------------------------------------
// MLP stage 1: fc1 (128->64) + BN1 + ReLU -> h1 (ws).
// K-loop rolled (#pragma unroll 1) so code fits the 32 KB I$ (round-1 failure
// was a ~60 KB unrolled body: VALUBusy 34%, occ 12%). Weight addresses are
// wave-uniform -> s_load; FMA = v_fmac_f32 with SGPR operand (free).
// ---------------------------------------------------------------------------
__global__ __launch_bounds__(256) void mlp1_kernel(
    const float* __restrict__ feature, const float* __restrict__ feature_geo,
    const float* __restrict__ w1, const float* __restrict__ b1,
    const float* __restrict__ g1, const float* __restrict__ be1,
    const float* __restrict__ m1, const float* __restrict__ v1,
    float* __restrict__ h1_out)
{
    const int n = blockIdx.x * 256 + threadIdx.x;
    float acc[DD];
#pragma unroll
    for (int j = 0; j < DD; ++j) acc[j] = 0.0f;

    const float4* fA = reinterpret_cast<const float4*>(feature) + (size_t)n * 16;
#pragma unroll 1
    for (int q = 0; q < 16; ++q) {
        const float4 fv = fA[q];
        const float* wr = w1 + q * 4 * DD;
#pragma unroll
        for (int j = 0; j < DD; ++j) acc[j] = fmaf(fv.x, wr[j], acc[j]);
#pragma unroll
        for (int j = 0; j < DD; ++j) acc[j] = fmaf(fv.y, wr[DD + j], acc[j]);
#pragma unroll
        for (int j = 0; j < DD; ++j) acc[j] = fmaf(fv.z, wr[2 * DD + j], acc[j]);
#pragma unroll
        for (int j = 0; j < DD; ++j) acc[j] = fmaf(fv.w, wr[3 * DD + j], acc[j]);
    }
    const float4* fB = reinterpret_cast<const float4*>(feature_geo) + (size_t)n * 16;
    const float* w1b = w1 + DD * DD;
#pragma unroll 1
    for (int q = 0; q < 16; ++q) {
        const float4 fv = fB[q];
        const float* wr = w1b + q * 4 * DD;
#pragma unroll
        for (int j = 0; j < DD; ++j) acc[j] = fmaf(fv.x, wr[j], acc[j]);
#pragma unroll
        for (int j = 0; j < DD; ++j) acc[j] = fmaf(fv.y, wr[DD + j], acc[j]);
#pragma unroll
        for (int j = 0; j < DD; ++j) acc[j] = fmaf(fv.z, wr[2 * DD + j], acc[j]);
#pragma unroll
        for (int j = 0; j < DD; ++j) acc[j] = fmaf(fv.w, wr[3 * DD + j], acc[j]);
    }
    // BN1 + ReLU
#pragma unroll
    for (int j = 0; j < DD; ++j) {
        float sc = g1[j] * (1.0f / sqrtf(v1[j] + 1e-5f));
        float h  = fmaf(acc[j] + b1[j] - m1[j], sc, be1[j]);
        acc[j] = fmaxf(h, 0.0f);
    }
    float4* o = reinterpret_cast<float4*>(h1_out) + (size_t)n * 16;
#pragma unroll
    for (int q = 0; q < 16; ++q)
        o[q] = make_float4(acc[4*q+0], acc[4*q+1], acc[4*q+2], acc[4*q+3]);
}

// ---------------------------------------------------------------------------
// MLP stage 2: fc2 (64->64) + BN2 + ReLU -> h2; fc3 (64->1) + ReLU -> score.
// ---------------------------------------------------------------------------
__global__ __launch_bounds__(256) void mlp2_kernel(
    const float* __restrict__ h1_in,
    const float* __restrict__ w2, const float* __restrict__ b2,
    const float* __restrict__ g2, const float* __restrict__ be2,
    const float* __restrict__ m2, const float* __restrict__ v2,
    const float* __restrict__ w3, const float* __restrict__ b3,
    float* __restrict__ h2_out, float* __restrict__ scores_out)
{
    const int n = blockIdx.x * 256 + threadIdx.x;
    float acc[DD];
#pragma unroll
    for (int j = 0; j < DD; ++j) acc[j] = 0.0f;

    const float4* fA = reinterpret_cast<const float4*>(h1_in) + (size_t)n * 16;
#pragma unroll 1
    for (int q = 0; q < 16; ++q) {
        const float4 fv = fA[q];
        const float* wr = w2 + q * 4 * DD;
#pragma unroll
        for (int j = 0; j < DD; ++j) acc[j] = fmaf(fv.x, wr[j], acc[j]);
#pragma unroll
        for (int j = 0; j < DD; ++j) acc[j] = fmaf(fv.y, wr[DD + j], acc[j]);
#pragma unroll
        for (int j = 0; j < DD; ++j) acc[j] = fmaf(fv.z, wr[2 * DD + j], acc[j]);
#pragma unroll
        for (int j = 0; j < DD; ++j) acc[j] = fmaf(fv.w, wr[3 * DD + j], acc[j]);
    }
    // BN2 + ReLU -> h2, fused fc3 dot
    float s = 0.0f;
#pragma unroll
    for (int j = 0; j < DD; ++j) {
        float sc = g2[j] * (1.0f / sqrtf(v2[j] + 1e-5f));
        float h  = fmaf(acc[j] + b2[j] - m2[j], sc, be2[j]);
        h = fmaxf(h, 0.0f);
        acc[j] = h;
        s = fmaf(h, w3[j], s);
    }
    s += b3[0];
    float4* o = reinterpret_cast<float4*>(h2_out) + (size_t)n * 16;
#pragma unroll
    for (int q = 0; q < 16; ++q)
        o[q] = make_float4(acc[4*q+0], acc[4*q+1], acc[4*q+2], acc[4*q+3]);
    scores_out[n] = fmaxf(s, 0.0f);
}

// ---------------------------------------------------------------------------
// Mask: per-(plane,point) masks + scores_masked + ballot hit bitmasks.
// Write-BW bound (537 MB). Plane params via wave-uniform loads from the
// packed array (const __restrict, uniform addr -> s_load_dwordx4, SMEM pipe;
// replaces round-2's 384 ds_read_b128/wave + barrier).
// ---------------------------------------------------------------------------
__global__ __launch_bounds__(256) void mask_kernel(
    const float* __restrict__ xyz, const float* __restrict__ centers,
    const float* __restrict__ packed,
    const float* __restrict__ scores,
    float* __restrict__ out_sm, float* __restrict__ out_mask,
    float* __restrict__ out_on, float* __restrict__ out_off,
    unsigned long long* __restrict__ hitOn, unsigned long long* __restrict__ hitOff)
{
    const int t = threadIdx.x;
    const int n = blockIdx.x * 256 + t;
    const float c0 = xyz[n*3+0] + centers[0];
    const float c1 = xyz[n*3+1] + centers[1];
    const float c2 = xyz[n*3+2] + centers[2];
    const float s  = scores[n];
    // sigmoid(s) > 0.5 via XLA-style logistic expansion (s >= 0 post-ReLU)
    const bool on  = (0.5f + 0.5f * tanhf(0.5f * s)) > 0.5f;
    const int lane = t & 63;
    const int word = n >> 6;

    const float4* pp = reinterpret_cast<const float4*>(packed);
#pragma unroll 1
    for (int p = 0; p < NP; ++p) {
        float4 nrm = pp[p*3+0];
        float4 mn  = pp[p*3+1];
        float4 mx  = pp[p*3+2];
        float d = fabsf(fmaf(c2, nrm.z, fmaf(c1, nrm.y, c0 * nrm.x)) - nrm.w);
        bool ok0 = (mx.x == 0.0f) | ((c0 >= mn.x) & (c0 < mx.x));
        bool ok1 = (mx.y == 0.0f) | ((c1 >= mn.y) & (c1 < mx.y));
        bool ok2 = (mx.z == 0.0f) | ((c2 >= mn.z) & (c2 < mx.z));
        bool mk  = ok0 & ok1 & ok2 & (d < 0.1f);
        size_t idx = (size_t)p * NPTS + n;
        out_sm[idx]   = mk ? s : 0.0f;
        out_mask[idx] = mk ? 1.0f : 0.0f;
        bool mon  = mk & on;
        bool moff = mk & (!on);
        out_on[idx]  = mon  ? 1.0f : 0.0f;
        out_off[idx] = moff ? 1.0f : 0.0f;
        unsigned long long bOn  = __ballot(mon);
        unsigned long long bOff = __ballot(moff);
        if (lane == 0) {
            hitOn [(size_t)p * NWORDS + word] = bOn;
            hitOff[(size_t)p * NWORDS + word] = bOff;
        }
    }
}

// ---------------------------------------------------------------------------
// Pool: masked max of h2 per plane, accumulated in registers per block, then
// atomicMax(int) straight into out_feats. Non-negative IEEE floats compare
// as signed ints, h2 >= 0, zero-init by prep -> exact where(any,max,0).
// Replaces round-2's partials (8 MB wr + 33 MB rd) + reduce kernel.
// Wave w owns planes [32w,32w+32); lane = dim; hit loop is wave-uniform.
// tile[n*64+lane]: 2-way bank alias = free (m136).
// ---------------------------------------------------------------------------
__global__ __launch_bounds__(256) void pool_kernel(
    const float* __restrict__ h2,
    const unsigned long long* __restrict__ hitOn,
    const unsigned long long* __restrict__ hitOff,
    int* __restrict__ out_feats_i)
{
    __shared__ float tile[128 * DD];                 // 32 KB
    __shared__ unsigned long long bm[2][NP][2];      // 4 KB
    const int t = threadIdx.x;
    const int lane = t & 63;
    const int wv = t >> 6;

    float accOn[32], accOff[32];
#pragma unroll
    for (int i = 0; i < 32; ++i) { accOn[i] = 0.0f; accOff[i] = 0.0f; }

    for (int cc = 0; cc < 4; ++cc) {
        const int chunk = blockIdx.x * 4 + cc;       // 0..2047
        const int base  = chunk * 128;
        const float4* src = reinterpret_cast<const float4*>(h2 + (size_t)base * DD);
        float4* dst = reinterpret_cast<float4*>(tile);
#pragma unroll
        for (int q = 0; q < 8; ++q) dst[t + q * 256] = src[t + q * 256];
        {
            const int p = t & 127;
            const int half = t >> 7;
            const unsigned long long* hsrc = half ? hitOff : hitOn;
            const int w0 = chunk * 2;
            bm[half][p][0] = hsrc[(size_t)p * NWORDS + w0 + 0];
            bm[half][p][1] = hsrc[(size_t)p * NWORDS + w0 + 1];
        }
        __syncthreads();

#pragma unroll
        for (int i = 0; i < 32; ++i) {
            const int p = wv * 32 + i;
            unsigned long long m;
            m = bm[0][p][0];
            while (m) { int nn = __builtin_ctzll(m); m &= m - 1;
                        accOn[i]  = fmaxf(accOn[i],  tile[nn * DD + lane]); }
            m = bm[0][p][1];
            while (m) { int nn = __builtin_ctzll(m); m &= m - 1;
                        accOn[i]  = fmaxf(accOn[i],  tile[(64 + nn) * DD + lane]); }
            m = bm[1][p][0];
            while (m) { int nn = __builtin_ctzll(m); m &= m - 1;
                        accOff[i] = fmaxf(accOff[i], tile[nn * DD + lane]); }
            m = bm[1][p][1];
            while (m) { int nn = __builtin_ctzll(m); m &= m - 1;
                        accOff[i] = fmaxf(accOff[i], tile[(64 + nn) * DD + lane]); }
        }
        __syncthreads();
    }
#pragma unroll
    for (int i = 0; i < 32; ++i) {
        const int p = wv * 32 + i;
        if (accOn[i]  != 0.0f) atomicMax(&out_feats_i[p * DD + lane],            __float_as_int(accOn[i]));
        if (accOff[i] != 0.0f) atomicMax(&out_feats_i[NP * DD + p * DD + lane],  __float_as_int(accOff[i]));
    }
}

extern "C" void kernel_launch(void* const* d_in, const int* in_sizes, int n_in,
                              void* d_out, int out_size, void* d_ws, size_t ws_size,
                              hipStream_t stream) {
    const float* feature      = (const float*)d_in[0];
    const float* feature_geo  = (const float*)d_in[1];
    const float* xyz          = (const float*)d_in[2];
    const float* centers      = (const float*)d_in[3];
    const float* plane_center = (const float*)d_in[4];
    const float* plane_normal = (const float*)d_in[5];
    const float* pmin         = (const float*)d_in[6];
    const float* pmax         = (const float*)d_in[7];
    const float* w1 = (const float*)d_in[8];
    const float* b1 = (const float*)d_in[9];
    const float* g1 = (const float*)d_in[10];
    const float* be1 = (const float*)d_in[11];
    const float* m1 = (const float*)d_in[12];
    const float* v1 = (const float*)d_in[13];
    const float* w2 = (const float*)d_in[14];
    const float* b2 = (const float*)d_in[15];
    const float* g2 = (const float*)d_in[16];
    const float* be2 = (const float*)d_in[17];
    const float* m2 = (const float*)d_in[18];
    const float* v2 = (const float*)d_in[19];
    const float* w3 = (const float*)d_in[20];
    const float* b3 = (const float*)d_in[21];

    float* out = (float*)d_out;
    const size_t PN = (size_t)NP * NPTS;
    float* out_sm    = out;
    float* out_mask  = out + PN;
    float* out_on    = out + 2 * PN;
    float* out_off   = out + 3 * PN;
    float* out_feats = out + 4 * PN;

    // workspace carve (~137 MB)
    float* h1     = (float*)d_ws;                                // N*64 f32 (64 MB)
    float* h2     = h1 + (size_t)NPTS * DD;                      // N*64 f32 (64 MB)
    float* scores = h2 + (size_t)NPTS * DD;                      // N f32
    unsigned long long* hitOn  = (unsigned long long*)(scores + NPTS);
    unsigned long long* hitOff = hitOn + (size_t)NP * NWORDS;
    float* packed = (float*)(hitOff + (size_t)NP * NWORDS);      // P*12 f32

    prep_kernel<<<64, 256, 0, stream>>>(
        plane_center, plane_normal, pmin, pmax, packed, out_feats);
    mlp1_kernel<<<NPTS / 256, 256, 0, stream>>>(
        feature, feature_geo, w1, b1, g1, be1, m1, v1, h1);
    mlp2_kernel<<<NPTS / 256, 256, 0, stream>>>(
        h1, w2, b2, g2, be2, m2, v2, w3, b3, h2, scores);
    mask_kernel<<<NPTS / 256, 256, 0, stream>>>(
        xyz, centers, packed, scores,
        out_sm, out_mask, out_on, out_off, hitOn, hitOff);
    pool_kernel<<<512, 256, 0, stream>>>(h2, hitOn, hitOff, (int*)out_feats);
}

// Round 4
// 842.532 us; speedup vs baseline: 2.7826x; 1.0319x over previous
//
#include <hip/hip_runtime.h>
#include <hip/hip_bf16.h>
#include <math.h>

// Problem constants (fixed by the reference file)
#define NPTS 262144
#define NP   128
#define DD   64
#define NWORDS (NPTS / 64)   // 4096 u64 ballot words per plane

// ---------------------------------------------------------------------------
// Prep: pack plane params to [P][12] floats (normal.xyz+offs | min.xyz | max.xyz)
// -> fused kernel reads them wave-uniformly (s_load, SMEM pipe, no LDS/barrier).
// Also zero out_feats (16384 floats) for the atomic-max pool (d_out is
// re-poisoned 0xAA before every timed launch).
// ---------------------------------------------------------------------------
__global__ __launch_bounds__(256) void prep_kernel(
    const float* __restrict__ plane_center, const float* __restrict__ plane_normal,
    const float* __restrict__ pmin, const float* __restrict__ pmax,
    float* __restrict__ packed, float* __restrict__ out_feats)
{
    const int t = threadIdx.x;
    out_feats[blockIdx.x * 256 + t] = 0.0f;          // grid = 64 blocks
    if (blockIdx.x == 0 && t < NP) {
        float n0 = plane_normal[t*3+0], n1 = plane_normal[t*3+1], n2 = plane_normal[t*3+2];
        float c0 = plane_center[t*3+0], c1 = plane_center[t*3+1], c2 = plane_center[t*3+2];
        float off = (c0*n0 + c1*n1) + c2*n2;          // matches jnp.sum order
        float4* pp = reinterpret_cast<float4*>(packed) + t * 3;
        pp[0] = make_float4(n0, n1, n2, off);
        pp[1] = make_float4(pmin[t*3+0], pmin[t*3+1], pmin[t*3+2], 0.0f);
        pp[2] = make_float4(pmax[t*3+0], pmax[t*3+1], pmax[t*3+2], 0.0f);
    }
}

// ---------------------------------------------------------------------------
// Fused per-point kernel: fc1(128->64)+BN1+ReLU, fc2(64->64)+BN2+ReLU -> h2,
// fc3(64->1)+ReLU -> score, then the 128-plane mask loop (4 output arrays +
// ballot bitmasks). Fusion rationale (round-4): kills the h1 round-trip
// (128 MB) and phase serialization — staggered blocks overlap FMA-dense fc
// phases with the store-dense mask phase, hiding ~55 us of VALU compute under
// the 537 MB write stream. K-loops rolled (#pragma unroll 1) to stay inside
// the 32 KB I$ (round-1 lesson: full unroll = 60 KB body, VALUBusy 34%).
// Weight/plane addresses are wave-uniform -> s_load on the SMEM pipe.
// Accumulation order identical to round-3 kernels (absmax must stay ~3e-8).
// ---------------------------------------------------------------------------
__global__ __launch_bounds__(256) void fused_kernel(
    const float* __restrict__ feature, const float* __restrict__ feature_geo,
    const float* __restrict__ xyz, const float* __restrict__ centers,
    const float* __restrict__ packed,
    const float* __restrict__ w1, const float* __restrict__ b1,
    const float* __restrict__ g1, const float* __restrict__ be1,
    const float* __restrict__ m1, const float* __restrict__ v1,
    const float* __restrict__ w2, const float* __restrict__ b2,
    const float* __restrict__ g2, const float* __restrict__ be2,
    const float* __restrict__ m2, const float* __restrict__ v2,
    const float* __restrict__ w3, const float* __restrict__ b3,
    float* __restrict__ h2_out,
    float* __restrict__ out_sm, float* __restrict__ out_mask,
    float* __restrict__ out_on, float* __restrict__ out_off,
    unsigned long long* __restrict__ hitOn, unsigned long long* __restrict__ hitOff)
{
    const int t = threadIdx.x;
    const int n = blockIdx.x * 256 + t;

    // cloud coords (needed at the end; loads issue early, latency hidden by fc1)
    const float c0 = xyz[n*3+0] + centers[0];
    const float c1 = xyz[n*3+1] + centers[1];
    const float c2 = xyz[n*3+2] + centers[2];

    float acc[DD];
#pragma unroll
    for (int j = 0; j < DD; ++j) acc[j] = 0.0f;

    // fc1 first half: feature
    const float4* fA = reinterpret_cast<const float4*>(feature) + (size_t)n * 16;
#pragma unroll 1
    for (int q = 0; q < 16; ++q) {
        const float4 fv = fA[q];
        const float* wr = w1 + q * 4 * DD;
#pragma unroll
        for (int j = 0; j < DD; ++j) acc[j] = fmaf(fv.x, wr[j], acc[j]);
#pragma unroll
        for (int j = 0; j < DD; ++j) acc[j] = fmaf(fv.y, wr[DD + j], acc[j]);
#pragma unroll
        for (int j = 0; j < DD; ++j) acc[j] = fmaf(fv.z, wr[2 * DD + j], acc[j]);
#pragma unroll
        for (int j = 0; j < DD; ++j) acc[j] = fmaf(fv.w, wr[3 * DD + j], acc[j]);
    }
    // fc1 second half: feature_geo
    const float4* fB = reinterpret_cast<const float4*>(feature_geo) + (size_t)n * 16;
    const float* w1b = w1 + DD * DD;
#pragma unroll 1
    for (int q = 0; q < 16; ++q) {
        const float4 fv = fB[q];
        const float* wr = w1b + q * 4 * DD;
#pragma unroll
        for (int j = 0; j < DD; ++j) acc[j] = fmaf(fv.x, wr[j], acc[j]);
#pragma unroll
        for (int j = 0; j < DD; ++j) acc[j] = fmaf(fv.y, wr[DD + j], acc[j]);
#pragma unroll
        for (int j = 0; j < DD; ++j) acc[j] = fmaf(fv.z, wr[2 * DD + j], acc[j]);
#pragma unroll
        for (int j = 0; j < DD; ++j) acc[j] = fmaf(fv.w, wr[3 * DD + j], acc[j]);
    }
    // BN1 + ReLU -> h1 (registers)
    float h1[DD];
#pragma unroll
    for (int j = 0; j < DD; ++j) {
        float sc = g1[j] * (1.0f / sqrtf(v1[j] + 1e-5f));
        float h  = fmaf(acc[j] + b1[j] - m1[j], sc, be1[j]);
        h1[j] = fmaxf(h, 0.0f);
        acc[j] = 0.0f;
    }
    // fc2 (same order as round-3 mlp2: q over 16, fv = h1[4q..4q+3])
#pragma unroll 1
    for (int q = 0; q < 16; ++q) {
        const float fx = h1[4*q+0], fy = h1[4*q+1], fz = h1[4*q+2], fw = h1[4*q+3];
        const float* wr = w2 + q * 4 * DD;
#pragma unroll
        for (int j = 0; j < DD; ++j) acc[j] = fmaf(fx, wr[j], acc[j]);
#pragma unroll
        for (int j = 0; j < DD; ++j) acc[j] = fmaf(fy, wr[DD + j], acc[j]);
#pragma unroll
        for (int j = 0; j < DD; ++j) acc[j] = fmaf(fz, wr[2 * DD + j], acc[j]);
#pragma unroll
        for (int j = 0; j < DD; ++j) acc[j] = fmaf(fw, wr[3 * DD + j], acc[j]);
    }
    // BN2 + ReLU -> h2, fused fc3 dot
    float s = 0.0f;
#pragma unroll
    for (int j = 0; j < DD; ++j) {
        float sc = g2[j] * (1.0f / sqrtf(v2[j] + 1e-5f));
        float h  = fmaf(acc[j] + b2[j] - m2[j], sc, be2[j]);
        h = fmaxf(h, 0.0f);
        acc[j] = h;
        s = fmaf(h, w3[j], s);
    }
    s += b3[0];
    const float score = fmaxf(s, 0.0f);

    // h2 store (acc[] dead after this -> registers free for mask loop)
    float4* o = reinterpret_cast<float4*>(h2_out) + (size_t)n * 16;
#pragma unroll
    for (int q = 0; q < 16; ++q)
        o[q] = make_float4(acc[4*q+0], acc[4*q+1], acc[4*q+2], acc[4*q+3]);

    // sigmoid(score) > 0.5 via XLA-style logistic expansion (score >= 0)
    const bool on  = (0.5f + 0.5f * tanhf(0.5f * score)) > 0.5f;
    const int lane = t & 63;
    const int word = n >> 6;

    const float4* pp = reinterpret_cast<const float4*>(packed);
#pragma unroll 1
    for (int p = 0; p < NP; ++p) {
        float4 nrm = pp[p*3+0];
        float4 mn  = pp[p*3+1];
        float4 mx  = pp[p*3+2];
        float d = fabsf(fmaf(c2, nrm.z, fmaf(c1, nrm.y, c0 * nrm.x)) - nrm.w);
        bool ok0 = (mx.x == 0.0f) | ((c0 >= mn.x) & (c0 < mx.x));
        bool ok1 = (mx.y == 0.0f) | ((c1 >= mn.y) & (c1 < mx.y));
        bool ok2 = (mx.z == 0.0f) | ((c2 >= mn.z) & (c2 < mx.z));
        bool mk  = ok0 & ok1 & ok2 & (d < 0.1f);
        size_t idx = (size_t)p * NPTS + n;
        out_sm[idx]   = mk ? score : 0.0f;
        out_mask[idx] = mk ? 1.0f : 0.0f;
        bool mon  = mk & on;
        bool moff = mk & (!on);
        out_on[idx]  = mon  ? 1.0f : 0.0f;
        out_off[idx] = moff ? 1.0f : 0.0f;
        unsigned long long bOn  = __ballot(mon);
        unsigned long long bOff = __ballot(moff);
        if (lane == 0) {
            hitOn [(size_t)p * NWORDS + word] = bOn;
            hitOff[(size_t)p * NWORDS + word] = bOff;
        }
    }
}

// ---------------------------------------------------------------------------
// Pool: masked max of h2 per plane, register-accumulated per block, then
// atomicMax(int) into out_feats (non-negative IEEE floats compare as signed
// ints; h2 >= 0; zero-init by prep -> exact where(any,max,0) semantics).
// Wave w owns planes [32w,32w+32); lane = dim; hit loop is wave-uniform.
// tile[n*64+lane]: 2-way bank alias = free (m136).
// ---------------------------------------------------------------------------
__global__ __launch_bounds__(256) void pool_kernel(
    const float* __restrict__ h2,
    const unsigned long long* __restrict__ hitOn,
    const unsigned long long* __restrict__ hitOff,
    int* __restrict__ out_feats_i)
{
    __shared__ float tile[128 * DD];                 // 32 KB
    __shared__ unsigned long long bm[2][NP][2];      // 4 KB
    const int t = threadIdx.x;
    const int lane = t & 63;
    const int wv = t >> 6;

    float accOn[32], accOff[32];
#pragma unroll
    for (int i = 0; i < 32; ++i) { accOn[i] = 0.0f; accOff[i] = 0.0f; }

    for (int cc = 0; cc < 4; ++cc) {
        const int chunk = blockIdx.x * 4 + cc;       // 0..2047
        const int base  = chunk * 128;
        const float4* src = reinterpret_cast<const float4*>(h2 + (size_t)base * DD);
        float4* dst = reinterpret_cast<float4*>(tile);
#pragma unroll
        for (int q = 0; q < 8; ++q) dst[t + q * 256] = src[t + q * 256];
        {
            const int p = t & 127;
            const int half = t >> 7;
            const unsigned long long* hsrc = half ? hitOff : hitOn;
            const int w0 = chunk * 2;
            bm[half][p][0] = hsrc[(size_t)p * NWORDS + w0 + 0];
            bm[half][p][1] = hsrc[(size_t)p * NWORDS + w0 + 1];
        }
        __syncthreads();

#pragma unroll
        for (int i = 0; i < 32; ++i) {
            const int p = wv * 32 + i;
            unsigned long long m;
            m = bm[0][p][0];
            while (m) { int nn = __builtin_ctzll(m); m &= m - 1;
                        accOn[i]  = fmaxf(accOn[i],  tile[nn * DD + lane]); }
            m = bm[0][p][1];
            while (m) { int nn = __builtin_ctzll(m); m &= m - 1;
                        accOn[i]  = fmaxf(accOn[i],  tile[(64 + nn) * DD + lane]); }
            m = bm[1][p][0];
            while (m) { int nn = __builtin_ctzll(m); m &= m - 1;
                        accOff[i] = fmaxf(accOff[i], tile[nn * DD + lane]); }
            m = bm[1][p][1];
            while (m) { int nn = __builtin_ctzll(m); m &= m - 1;
                        accOff[i] = fmaxf(accOff[i], tile[(64 + nn) * DD + lane]); }
        }
        __syncthreads();
    }
#pragma unroll
    for (int i = 0; i < 32; ++i) {
        const int p = wv * 32 + i;
        if (accOn[i]  != 0.0f) atomicMax(&out_feats_i[p * DD + lane],            __float_as_int(accOn[i]));
        if (accOff[i] != 0.0f) atomicMax(&out_feats_i[NP * DD + p * DD + lane],  __float_as_int(accOff[i]));
    }
}

extern "C" void kernel_launch(void* const* d_in, const int* in_sizes, int n_in,
                              void* d_out, int out_size, void* d_ws, size_t ws_size,
                              hipStream_t stream) {
    const float* feature      = (const float*)d_in[0];
    const float* feature_geo  = (const float*)d_in[1];
    const float* xyz          = (const float*)d_in[2];
    const float* centers      = (const float*)d_in[3];
    const float* plane_center = (const float*)d_in[4];
    const float* plane_normal = (const float*)d_in[5];
    const float* pmin         = (const float*)d_in[6];
    const float* pmax         = (const float*)d_in[7];
    const float* w1 = (const float*)d_in[8];
    const float* b1 = (const float*)d_in[9];
    const float* g1 = (const float*)d_in[10];
    const float* be1 = (const float*)d_in[11];
    const float* m1 = (const float*)d_in[12];
    const float* v1 = (const float*)d_in[13];
    const float* w2 = (const float*)d_in[14];
    const float* b2 = (const float*)d_in[15];
    const float* g2 = (const float*)d_in[16];
    const float* be2 = (const float*)d_in[17];
    const float* m2 = (const float*)d_in[18];
    const float* v2 = (const float*)d_in[19];
    const float* w3 = (const float*)d_in[20];
    const float* b3 = (const float*)d_in[21];

    float* out = (float*)d_out;
    const size_t PN = (size_t)NP * NPTS;
    float* out_sm    = out;
    float* out_mask  = out + PN;
    float* out_on    = out + 2 * PN;
    float* out_off   = out + 3 * PN;
    float* out_feats = out + 4 * PN;

    // workspace carve (~73 MB)
    float* h2     = (float*)d_ws;                                // N*64 f32 (64 MB)
    unsigned long long* hitOn  = (unsigned long long*)(h2 + (size_t)NPTS * DD);
    unsigned long long* hitOff = hitOn + (size_t)NP * NWORDS;
    float* packed = (float*)(hitOff + (size_t)NP * NWORDS);      // P*12 f32

    prep_kernel<<<64, 256, 0, stream>>>(
        plane_center, plane_normal, pmin, pmax, packed, out_feats);
    fused_kernel<<<NPTS / 256, 256, 0, stream>>>(
        feature, feature_geo, xyz, centers, packed,
        w1, b1, g1, be1, m1, v1, w2, b2, g2, be2, m2, v2, w3, b3,
        h2, out_sm, out_mask, out_on, out_off, hitOn, hitOff);
    pool_kernel<<<512, 256, 0, stream>>>(h2, hitOn, hitOff, (int*)out_feats);
}